// Round 7
// baseline (21.878 us; speedup 1.0000x reference)
//
#include <hip/hip_runtime.h>

// DynamicMaskHead fused kernel — merged-slice software pipeline.
// Grid: 1024 blocks = 128 instances x 8 slice-PAIRS (24 output rows each).
// All blocks co-resident (4 blocks/CU) -> single dispatch round.
// Per block: issue 16 dwordx4 feature loads up front (tile B's 8 loads in
// flight during tile A's MLP), MLP A -> m0, MLP B -> m1, ONE barrier,
// then 24 rows of bilinear+sigmoid with coalesced dword stores.

#define HH 192
#define WW 256
#define IH 96
#define IW 128
#define HW (HH * WW)

__global__ __launch_bounds__(256, 4) void dmh_kernel(
    const float* __restrict__ mf,      // (2,8,192,256)
    const float* __restrict__ params,  // (128,169)
    const float* __restrict__ locs,    // (128,2)
    const int*   __restrict__ im_inds, // (128)
    const int*   __restrict__ fpn,     // (128)
    const int*   __restrict__ stride_p,// (1)
    float*       __restrict__ out)     // (128,1,192,256)
{
    __shared__ float m0[8 * IW];       // 4 KB: mask rows for tile A
    __shared__ float m1[8 * IW];       // 4 KB: mask rows for tile B

    const int bx   = blockIdx.x;
    const int inst = bx >> 3;
    const int j    = bx & 7;
    const int tid  = threadIdx.x;

    const int   s   = stride_p[0];     // 8
    const int   sh  = s >> 1;          // 4
    const float ix  = locs[2 * inst + 0];
    const float iy  = locs[2 * inst + 1];
    const float inv_soi = 1.0f / (float)(64 << fpn[inst]); // SOI are pow2
    const int   im  = im_inds[inst];

    // grid-cell selection (matches jnp: clip then true f32 divide, floor)
    const float nlx = ix * 0.125f;
    const float nly = iy * 0.125f;
    const int gx = (int)floorf(fminf(fmaxf(nlx, 0.0f), (float)(WW - 1)) / (float)(WW / 2));
    const int gy = (int)floorf(fminf(fmaxf(nly, 0.0f), (float)(HH - 1)) / (float)(HH / 2));

    const float* __restrict__ p = params + inst * 169;

    const int orowA = j * 24;                                 // tile A out rows
    const int orowB = orowA + 12;                             // tile B out rows
    const int msA   = (int)((float)orowA * (95.0f / 191.0f));
    const int msB   = (int)((float)orowB * (95.0f / 191.0f));

    // ---------------- Phase 1: 2 tiles x 8 mask rows into LDS ---------------
    {
        const int col4 = (tid & 31) * 4;       // 0,4,...,124
        const int r    = tid >> 5;             // 0..7 (one mask row/thread/tile)
        int grA = msA + r; if (grA > IH - 1) grA = IH - 1;
        int grB = msB + r; if (grB > IH - 1) grB = IH - 1;
        const int hA = gy * IH + grA;
        const int hB = gy * IH + grB;
        const float relyA = (iy - (float)(hA * s + sh)) * inv_soi;
        const float relyB = (iy - (float)(hB * s + sh)) * inv_soi;

        const float* fcol = mf + (size_t)(im * 8) * HW + gx * IW + col4;

        // all 16 loads issued up front; B's 8 stay in flight during MLP A
        float4 FA[8], FB[8];
        #pragma unroll
        for (int c = 0; c < 8; ++c)
            FA[c] = *(const float4*)(fcol + (size_t)hA * WW + (size_t)c * HW);
        #pragma unroll
        for (int c = 0; c < 8; ++c)
            FB[c] = *(const float4*)(fcol + (size_t)hB * WW + (size_t)c * HW);

        const float relx0 = (ix - (float)((gx * IW + col4) * s + sh)) * inv_soi;
        const float dstep = (float)s * inv_soi;

        // ---- MLP for tile A: 4 sequential per-px chains (low VGPR) ----
        float4 resA;
        float* rvA = &resA.x;
        #pragma unroll
        for (int jp = 0; jp < 4; ++jp) {
            const float relx = relx0 - (float)jp * dstep;
            float f[8];
            #pragma unroll
            for (int c = 0; c < 8; ++c) f[c] = ((const float*)&FA[c])[jp];
            float a[8];
            #pragma unroll
            for (int k = 0; k < 8; ++k) {
                float acc = p[152 + k];
                acc = fmaf(p[k * 10 + 0], relx, acc);
                acc = fmaf(p[k * 10 + 1], relyA, acc);
                #pragma unroll
                for (int c = 0; c < 8; ++c)
                    acc = fmaf(p[k * 10 + 2 + c], f[c], acc);
                a[k] = fmaxf(acc, 0.0f);
            }
            float b[8];
            #pragma unroll
            for (int k = 0; k < 8; ++k) {
                float acc = p[160 + k];
                #pragma unroll
                for (int c = 0; c < 8; ++c)
                    acc = fmaf(p[80 + k * 8 + c], a[c], acc);
                b[k] = fmaxf(acc, 0.0f);
            }
            float acc = p[168];
            #pragma unroll
            for (int c = 0; c < 8; ++c)
                acc = fmaf(p[144 + c], b[c], acc);
            rvA[jp] = acc;
        }
        *(float4*)&m0[r * IW + col4] = resA;

        // ---- MLP for tile B ----
        float4 resB;
        float* rvB = &resB.x;
        #pragma unroll
        for (int jp = 0; jp < 4; ++jp) {
            const float relx = relx0 - (float)jp * dstep;
            float f[8];
            #pragma unroll
            for (int c = 0; c < 8; ++c) f[c] = ((const float*)&FB[c])[jp];
            float a[8];
            #pragma unroll
            for (int k = 0; k < 8; ++k) {
                float acc = p[152 + k];
                acc = fmaf(p[k * 10 + 0], relx, acc);
                acc = fmaf(p[k * 10 + 1], relyB, acc);
                #pragma unroll
                for (int c = 0; c < 8; ++c)
                    acc = fmaf(p[k * 10 + 2 + c], f[c], acc);
                a[k] = fmaxf(acc, 0.0f);
            }
            float b[8];
            #pragma unroll
            for (int k = 0; k < 8; ++k) {
                float acc = p[160 + k];
                #pragma unroll
                for (int c = 0; c < 8; ++c)
                    acc = fmaf(p[80 + k * 8 + c], a[c], acc);
                b[k] = fmaxf(acc, 0.0f);
            }
            float acc = p[168];
            #pragma unroll
            for (int c = 0; c < 8; ++c)
                acc = fmaf(p[144 + c], b[c], acc);
            rvB[jp] = acc;
        }
        *(float4*)&m1[r * IW + col4] = resB;
    }
    __syncthreads();

    // ------- Phase 2: one output column/thread, 24 rows, sigmoid ------------
    {
        const int ocol = tid;                                  // 0..255
        const float wpos = (float)ocol * (127.0f / 255.0f);
        int wlo = (int)wpos; if (wlo > IW - 2) wlo = IW - 2;
        const float fw = wpos - (float)wlo;

        float* opA = out + (size_t)inst * HW + (size_t)orowA * WW + ocol;

        #pragma unroll
        for (int r = 0; r < 12; ++r) {
            const float hpos = (float)(orowA + r) * (95.0f / 191.0f);
            int hlo = (int)hpos; if (hlo > IH - 2) hlo = IH - 2;
            const float fh = hpos - (float)hlo;
            const int rl = hlo - msA;                          // uniform

            const float* mp = &m0[rl * IW + wlo];
            const float v00 = mp[0];
            const float v01 = mp[1];
            const float v10 = mp[IW];
            const float v11 = mp[IW + 1];

            const float top = fmaf(fw, v01 - v00, v00);
            const float bot = fmaf(fw, v11 - v10, v10);
            const float val = fmaf(fh, bot - top, top);
            opA[(size_t)r * WW] = 1.0f / (1.0f + __expf(-val));
        }

        float* opB = out + (size_t)inst * HW + (size_t)orowB * WW + ocol;

        #pragma unroll
        for (int r = 0; r < 12; ++r) {
            const float hpos = (float)(orowB + r) * (95.0f / 191.0f);
            int hlo = (int)hpos; if (hlo > IH - 2) hlo = IH - 2;
            const float fh = hpos - (float)hlo;
            const int rl = hlo - msB;                          // uniform

            const float* mp = &m1[rl * IW + wlo];
            const float v00 = mp[0];
            const float v01 = mp[1];
            const float v10 = mp[IW];
            const float v11 = mp[IW + 1];

            const float top = fmaf(fw, v01 - v00, v00);
            const float bot = fmaf(fw, v11 - v10, v10);
            const float val = fmaf(fh, bot - top, top);
            opB[(size_t)r * WW] = 1.0f / (1.0f + __expf(-val));
        }
    }
}

extern "C" void kernel_launch(void* const* d_in, const int* in_sizes, int n_in,
                              void* d_out, int out_size, void* d_ws, size_t ws_size,
                              hipStream_t stream) {
    const float* mf       = (const float*)d_in[0];
    const float* params   = (const float*)d_in[1];
    const float* locs     = (const float*)d_in[2];
    const int*   im_inds  = (const int*)d_in[3];
    const int*   fpn      = (const int*)d_in[4];
    const int*   stride_p = (const int*)d_in[5];
    float*       out      = (float*)d_out;

    dmh_kernel<<<dim3(1024), dim3(256), 0, stream>>>(
        mf, params, locs, im_inds, fpn, stride_p, out);
}

// Round 8
// 21.492 us; speedup vs baseline: 1.0179x; 1.0179x over previous
//
#include <hip/hip_runtime.h>

// DynamicMaskHead fused kernel — instruction-diet round.
// Grid: 1024 blocks = 128 instances x 8 slices of 24 output rows.
// Phase 1: tight 14-row mask window (vs 16 redundant) into 7 KB LDS;
//          thread = (row, 4 adjacent cols), 8x dwordx4 loads, r3-style
//          sequential per-px MLP chains. 2 passes (rows 0-7, 8-13).
// Phase 2: thread = 1 output col x 24 rows; hlo computed with INTEGER
//          (SALU, wave-uniform) math -> s_cbranch row walk that loads only
//          2 new LDS values when the source row advances (register reuse).

#define HH 192
#define WW 256
#define IH 96
#define IW 128
#define HW (HH * WW)

__global__ __launch_bounds__(256, 4) void dmh_kernel(
    const float* __restrict__ mf,      // (2,8,192,256)
    const float* __restrict__ params,  // (128,169)
    const float* __restrict__ locs,    // (128,2)
    const int*   __restrict__ im_inds, // (128)
    const int*   __restrict__ fpn,     // (128)
    const int*   __restrict__ stride_p,// (1)
    float*       __restrict__ out)     // (128,1,192,256)
{
    __shared__ float m[14 * IW];       // 7 KB mask-row stage

    const int bx   = blockIdx.x;
    const int inst = bx >> 3;
    const int j    = bx & 7;
    const int tid  = threadIdx.x;

    const int   s   = stride_p[0];     // 8
    const int   sh  = s >> 1;          // 4
    const float ix  = locs[2 * inst + 0];
    const float iy  = locs[2 * inst + 1];
    const float inv_soi = 1.0f / (float)(64 << fpn[inst]); // SOI are pow2
    const int   im  = im_inds[inst];

    // grid-cell selection (matches jnp: clip then true f32 divide, floor)
    const float nlx = ix * 0.125f;
    const float nly = iy * 0.125f;
    const int gx = (int)floorf(fminf(fmaxf(nlx, 0.0f), (float)(WW - 1)) / (float)(WW / 2));
    const int gy = (int)floorf(fminf(fmaxf(nly, 0.0f), (float)(HH - 1)) / (float)(HH / 2));

    const float* __restrict__ p = params + inst * 169;

    const int orow0 = j * 24;                  // first output row of this block
    const int ms    = (orow0 * 95) / 191;      // == floor(orow0*95f/191f), SALU

    // ------- Phase 1: mask rows [ms, ms+13] into LDS; 2 passes -------------
    {
        const int col4 = (tid & 31) * 4;       // 0,4,...,124
        const int rs   = tid >> 5;             // 0..7 (row slot)
        const float relx0 = (ix - (float)((gx * IW + col4) * s + sh)) * inv_soi;
        const float dstep = (float)s * inv_soi;
        const float* fcol = mf + (size_t)(im * 8) * HW + gx * IW + col4;

        #pragma unroll
        for (int pass = 0; pass < 2; ++pass) {
            const int r = rs + pass * 8;       // 0..15
            if (r < 14) {                      // wave-uniform skip (rows 14,15)
                int gr = ms + r; if (gr > IH - 1) gr = IH - 1;
                const int h = gy * IH + gr;
                const float rely = (iy - (float)(h * s + sh)) * inv_soi;

                const float* fbase = fcol + (size_t)h * WW;
                float4 F[8];
                #pragma unroll
                for (int c = 0; c < 8; ++c)
                    F[c] = *(const float4*)(fbase + (size_t)c * HW);

                float4 res;
                float* rv = &res.x;
                #pragma unroll
                for (int jp = 0; jp < 4; ++jp) {
                    const float relx = relx0 - (float)jp * dstep;
                    float f[8];
                    #pragma unroll
                    for (int c = 0; c < 8; ++c) f[c] = ((const float*)&F[c])[jp];
                    float a[8];
                    #pragma unroll
                    for (int k = 0; k < 8; ++k) {
                        float acc = p[152 + k];
                        acc = fmaf(p[k * 10 + 0], relx, acc);
                        acc = fmaf(p[k * 10 + 1], rely, acc);
                        #pragma unroll
                        for (int c = 0; c < 8; ++c)
                            acc = fmaf(p[k * 10 + 2 + c], f[c], acc);
                        a[k] = fmaxf(acc, 0.0f);
                    }
                    float b[8];
                    #pragma unroll
                    for (int k = 0; k < 8; ++k) {
                        float acc = p[160 + k];
                        #pragma unroll
                        for (int c = 0; c < 8; ++c)
                            acc = fmaf(p[80 + k * 8 + c], a[c], acc);
                        b[k] = fmaxf(acc, 0.0f);
                    }
                    float acc = p[168];
                    #pragma unroll
                    for (int c = 0; c < 8; ++c)
                        acc = fmaf(p[144 + c], b[c], acc);
                    rv[jp] = acc;
                }
                *(float4*)&m[r * IW + col4] = res;
            }
        }
    }
    __syncthreads();

    // ------- Phase 2: 1 col/thread x 24 rows; uniform row walk --------------
    {
        const int ocol = tid;                                  // 0..255
        const float wpos = (float)ocol * (127.0f / 255.0f);
        int wlo = (int)wpos; if (wlo > IW - 2) wlo = IW - 2;
        const float fw = wpos - (float)wlo;

        float* op = out + (size_t)inst * HW + (size_t)orow0 * WW + ocol;

        // r = 0: rl is always 0
        float v00 = m[wlo];
        float v01 = m[wlo + 1];
        float v10 = m[IW + wlo];
        float v11 = m[IW + wlo + 1];
        int cur = 0;
        {
            const float fh = (float)orow0 * (95.0f / 191.0f) - (float)ms;
            const float top = fmaf(fw, v01 - v00, v00);
            const float bot = fmaf(fw, v11 - v10, v10);
            const float val = fmaf(fh, bot - top, top);
            op[0] = 1.0f / (1.0f + __expf(-val));
        }

        #pragma unroll
        for (int r = 1; r < 24; ++r) {
            const int orow = orow0 + r;
            int ihlo = (orow * 95) / 191;      // SALU integer floor
            if (ihlo > IH - 2) ihlo = IH - 2;  // clamp (j=7, r=23 only)
            const float fh = (float)orow * (95.0f / 191.0f) - (float)ihlo;
            const int rl = ihlo - ms;          // wave-uniform, steps +0/+1

            if (rl != cur) {                   // uniform branch (SALU cmp)
                v00 = v10; v01 = v11;          // row advance: reuse bottom row
                v10 = m[(rl + 1) * IW + wlo];
                v11 = m[(rl + 1) * IW + wlo + 1];
                cur = rl;
            }
            const float top = fmaf(fw, v01 - v00, v00);
            const float bot = fmaf(fw, v11 - v10, v10);
            const float val = fmaf(fh, bot - top, top);
            op[(size_t)r * WW] = 1.0f / (1.0f + __expf(-val));
        }
    }
}

extern "C" void kernel_launch(void* const* d_in, const int* in_sizes, int n_in,
                              void* d_out, int out_size, void* d_ws, size_t ws_size,
                              hipStream_t stream) {
    const float* mf       = (const float*)d_in[0];
    const float* params   = (const float*)d_in[1];
    const float* locs     = (const float*)d_in[2];
    const int*   im_inds  = (const int*)d_in[3];
    const int*   fpn      = (const int*)d_in[4];
    const int*   stride_p = (const int*)d_in[5];
    float*       out      = (float*)d_out;

    dmh_kernel<<<dim3(1024), dim3(256), 0, stream>>>(
        mf, params, locs, im_inds, fpn, stride_p, out);
}